// Round 10
// baseline (100.847 us; speedup 1.0000x reference)
//
#include <hip/hip_runtime.h>

// GCN forward: algebraic collapse + LDS-staged split-bf16 MFMA GEMM (Wf fully in
// 128KB LDS, 8 waves x 32 rows per block) + bucket-sort CSR build with LDS-sorted
// coalesced writes + L2-resident [N,2] gathers. 6 launches:
//   k_prep    : Wf split + Wbig/u/v consts + zero(cur)
//   k_scatter : LDS hist -> reserve -> LDS-sort -> coalesced bucket write
//   k_p2      : per-bucket LDS sort -> rp/dis/csr (linear csr writes)
//   k_gemm    : merged main+mask GEMM, Wf staged in LDS
//   k_gather1 : T2 = dis*(dis*(agg_dis(P)) + u)
//   k_gather2 : out = (dis*agg(T2) + v) * Pm
// Math:  Z = Â(Â(X1@Wbig) + 1⊗u) + 1⊗v,  Â = D^-1/2 (A+I) D^-1/2
//        out = Z * (lrelu((F-MF)@W_in+b_in)@W_out + b_out)

#define NEG_SLOPE 0.01f
constexpr int HD = 256;
constexpr int CHUNK = 4096;   // edges per scatter block (196 blocks)
constexpr int BSTRIDE = 8192; // packed bucket capacity (expected ~4082)

typedef __bf16 bf16x8 __attribute__((ext_vector_type(8)));
typedef unsigned short u16x8 __attribute__((ext_vector_type(8)));
typedef float f32x4 __attribute__((ext_vector_type(4)));

#define MFMA16 __builtin_amdgcn_mfma_f32_16x16x32_bf16

// split fp32 -> bf16 hi (truncate) + bf16 lo (RNE of remainder)
__device__ inline void split1(float v, unsigned short& h, unsigned short& l) {
  unsigned u = __float_as_uint(v);
  unsigned hb = u & 0xFFFF0000u;
  float lf = v - __uint_as_float(hb);
  unsigned ul = __float_as_uint(lf);
  h = (unsigned short)(hb >> 16);
  l = (unsigned short)((ul + 0x7FFFu + ((ul >> 16) & 1u)) >> 16);
}

// ---------------- prep: W-split + consts + zero(cur) ----------------
__global__ __launch_bounds__(256) void k_prep(
    const float* __restrict__ Win, u16x8* __restrict__ Wf,
    const float* __restrict__ Wg1, const float* __restrict__ Wg2,
    const float* __restrict__ Wo, const float* __restrict__ bg1,
    const float* __restrict__ bg2, const float* __restrict__ bo,
    float* __restrict__ wb, float* __restrict__ uv, int* __restrict__ cur) {
  __shared__ float wt[256][2];
  const int bid = blockIdx.x, tid = threadIdx.x;
  if (bid < 32) {
    // fragment f = nt*8 + ks*2 + hl; lane's 8 elems:
    //   Win[ks*32 + (lane>>4)*8 + j][nt*16 + (lane&15)]
    int f = bid * 4 + (tid >> 6);
    int lane = tid & 63;
    int nt = f >> 3, ks = (f >> 1) & 3, hl = f & 1;
    int n = nt * 16 + (lane & 15);
    int k0 = ks * 32 + (lane >> 4) * 8;
    u16x8 outv;
    #pragma unroll
    for (int j = 0; j < 8; ++j) {
      unsigned short h, l;
      split1(Win[(size_t)(k0 + j) * HD + n], h, l);
      outv[j] = hl ? l : h;
    }
    Wf[f * 64 + lane] = outv;
  } else if (bid == 32) {
    int r = tid;
    float s0 = 0.f, s1 = 0.f;
    for (int k = 0; k < 256; ++k) {
      float w = Wg2[r * 256 + k];
      s0 = fmaf(w, Wo[k * 2 + 0], s0);
      s1 = fmaf(w, Wo[k * 2 + 1], s1);
    }
    wt[r][0] = s0; wt[r][1] = s1;
    __syncthreads();
    float b0 = 0.f, b1 = 0.f;
    for (int k = 0; k < 256; ++k) {
      float w = Wg1[r * 256 + k];
      b0 = fmaf(w, wt[k][0], b0);
      b1 = fmaf(w, wt[k][1], b1);
    }
    wb[r * 2 + 0] = b0; wb[r * 2 + 1] = b1;
    if (r < 2) {
      float u = 0.f, v = 0.f;
      for (int k = 0; k < 256; ++k) {
        u = fmaf(bg1[k], wt[k][r], u);
        v = fmaf(bg2[k], Wo[k * 2 + r], v);
      }
      uv[r] = u;             // u[c]
      uv[2 + r] = v + bo[r]; // v[c]
    }
  } else {
    cur[tid] = 0;
  }
}

// ---------------- scatter: LDS hist+sort, coalesced per-bin global writes -------
__global__ __launch_bounds__(256) void k_scatter(
    const int* __restrict__ src, const int* __restrict__ dst,
    int* __restrict__ cur, unsigned* __restrict__ packed, int E) {
  __shared__ int bins[256], lstart[256], gbase[256], lcur[256];
  __shared__ int wsum[4];
  __shared__ unsigned sbuf[CHUNK]; // 16 KB
  const int t = threadIdx.x, b = blockIdx.x;
  const int lane = t & 63, wid = t >> 6;
  bins[t] = 0;
  __syncthreads();
  const int e0 = b * CHUNK, e1 = min(e0 + CHUNK, E), m = e1 - e0;
  for (int e = e0 + t; e < e1; e += 256)
    atomicAdd(&bins[dst[e] >> 8], 1);
  __syncthreads();
  // exclusive scan of bins -> lstart; reserve global ranges
  {
    int v = bins[t], incl = v;
    #pragma unroll
    for (int o = 1; o < 64; o <<= 1) {
      int tmp = __shfl_up(incl, o, 64);
      if (lane >= o) incl += tmp;
    }
    if (lane == 63) wsum[wid] = incl;
    __syncthreads();
    int woff = 0;
    for (int w = 0; w < wid; ++w) woff += wsum[w];
    int st = woff + incl - v;
    lstart[t] = st;
    lcur[t] = st;
    gbase[t] = v ? atomicAdd(&cur[t], v) : 0;
  }
  __syncthreads();
  // LDS-sort the chunk by bin
  for (int e = e0 + t; e < e1; e += 256) {
    int d = dst[e], s = src[e];
    int slot = atomicAdd(&lcur[d >> 8], 1);
    sbuf[slot] = ((unsigned)d << 16) | (unsigned)s;
  }
  __syncthreads();
  // coalesced copy-out: per-bin contiguous runs
  for (int i = t; i < m; i += 256) {
    unsigned pv = sbuf[i];
    int bin = pv >> 24;
    packed[(size_t)bin * BSTRIDE + gbase[bin] + (i - lstart[bin])] = pv;
  }
}

// ---------------- p2: per-bucket LDS sort -> rp/dis/csr (linear writes) ---------
__global__ __launch_bounds__(256) void k_p2(
    const unsigned* __restrict__ packed, const int* __restrict__ cur,
    int* __restrict__ rp, float4* __restrict__ q, int* __restrict__ csr, int N) {
  __shared__ int cnt[256], sc[256];
  __shared__ int wsum[4];
  __shared__ unsigned short sbuf[BSTRIDE]; // 16 KB
  const int t = threadIdx.x;
  const int B = blockIdx.x;
  const int lane = t & 63, wid = t >> 6;
  // global bucket base = exclusive scan of cur at index B
  int tot = cur[t], incl = tot;
  #pragma unroll
  for (int o = 1; o < 64; o <<= 1) {
    int tmp = __shfl_up(incl, o, 64);
    if (lane >= o) incl += tmp;
  }
  if (lane == 63) wsum[wid] = incl;
  __syncthreads();
  int woff = 0;
  for (int w = 0; w < wid; ++w) woff += wsum[w];
  sc[t] = woff + incl - tot;
  __syncthreads();
  const int base = sc[B];
  const int ecnt = cur[B];
  const unsigned* pk = packed + (size_t)B * BSTRIDE;
  cnt[t] = 0;
  __syncthreads();
  for (int i = t; i < ecnt; i += 256)
    atomicAdd(&cnt[(pk[i] >> 16) & 0xFF], 1);
  __syncthreads();
  int v = cnt[t];
  incl = v;
  #pragma unroll
  for (int o = 1; o < 64; o <<= 1) {
    int tmp = __shfl_up(incl, o, 64);
    if (lane >= o) incl += tmp;
  }
  if (lane == 63) wsum[wid] = incl;
  __syncthreads();
  woff = 0;
  for (int w = 0; w < wid; ++w) woff += wsum[w];
  const int off = woff + incl - v;
  const int node = B * 256 + t;
  if (node < N) {
    rp[node] = base + off;
    ((float*)&q[node])[0] = rsqrtf((float)(v + 1)); // dis (+1 self-loop)
  } else if (node == N) {
    rp[N] = base + off; // == E
  }
  __syncthreads();
  cnt[t] = off; // LDS cursor
  __syncthreads();
  // LDS-sort src by low-8 dst, then linear coalesced copy to csr
  for (int i = t; i < ecnt; i += 256) {
    unsigned pv = pk[i];
    int slot = atomicAdd(&cnt[(pv >> 16) & 0xFF], 1);
    sbuf[slot] = (unsigned short)(pv & 0xFFFFu);
  }
  __syncthreads();
  for (int i = t; i < ecnt; i += 256)
    csr[base + i] = (int)sbuf[i];
}

// ---------------- GEMM: Wf in LDS, 8 waves x 32 rows, merged main+mask ----------
__global__ __launch_bounds__(512, 2) void k_gemm(
    const float* __restrict__ mf, const float* __restrict__ fe,
    const u16x8* __restrict__ Wf, const float* __restrict__ bi,
    const float* __restrict__ wb, const float* __restrict__ Wo,
    const float* __restrict__ bo, float4* __restrict__ q,
    float* __restrict__ Pm, int M) {
  __shared__ u16x8 sWf[8192]; // 128 KB: the whole fragment-ordered W (hi+lo)
  const int tid = threadIdx.x;
  #pragma unroll
  for (int i = 0; i < 16; ++i) sWf[tid + i * 512] = Wf[tid + i * 512];
  const int lane = tid & 63, wid = tid >> 6;
  const int base = blockIdx.x * 256 + wid * 32; // 8 waves x 32 rows
  const int kb = (lane >> 4) * 8;

  // A fragments: two 16-row halves, both branches (main=MF, mask=FE-MF), hi/lo
  bf16x8 ahi[2][4], alo[2][4], mhi[2][4], mlo[2][4];
  #pragma unroll
  for (int h = 0; h < 2; ++h) {
    int arow = base + h * 16 + (lane & 15);
    if (arow >= M) arow = M - 1;
    const float* ap = mf + (size_t)arow * 128 + kb;
    const float* fp = fe + (size_t)arow * 128 + kb;
    #pragma unroll
    for (int ks = 0; ks < 4; ++ks) {
      float x[8], y[8];
      *(float4*)&x[0] = *(const float4*)(ap + ks * 32);
      *(float4*)&x[4] = *(const float4*)(ap + ks * 32 + 4);
      *(float4*)&y[0] = *(const float4*)(fp + ks * 32);
      *(float4*)&y[4] = *(const float4*)(fp + ks * 32 + 4);
      u16x8 hA, lA, hM, lM;
      #pragma unroll
      for (int j = 0; j < 8; ++j) {
        unsigned short hh, ll;
        split1(x[j], hh, ll);        hA[j] = hh; lA[j] = ll;
        split1(y[j] - x[j], hh, ll); hM[j] = hh; lM[j] = ll;
      }
      ahi[h][ks] = __builtin_bit_cast(bf16x8, hA);
      alo[h][ks] = __builtin_bit_cast(bf16x8, lA);
      mhi[h][ks] = __builtin_bit_cast(bf16x8, hM);
      mlo[h][ks] = __builtin_bit_cast(bf16x8, lM);
    }
  }
  __syncthreads(); // staging complete

  float s0[2][4] = {}, s1[2][4] = {}, t0[2][4] = {}, t1[2][4] = {};
  #pragma unroll 1
  for (int nt = 0; nt < 16; ++nt) {
    f32x4 aM[2] = {{0,0,0,0},{0,0,0,0}}, aK[2] = {{0,0,0,0},{0,0,0,0}};
    #pragma unroll
    for (int ks = 0; ks < 4; ++ks) {
      bf16x8 bh = __builtin_bit_cast(bf16x8, sWf[(nt * 8 + ks * 2 + 0) * 64 + lane]);
      bf16x8 bl = __builtin_bit_cast(bf16x8, sWf[(nt * 8 + ks * 2 + 1) * 64 + lane]);
      #pragma unroll
      for (int h = 0; h < 2; ++h) {
        aM[h] = MFMA16(ahi[h][ks], bh, aM[h], 0, 0, 0);
        aM[h] = MFMA16(alo[h][ks], bh, aM[h], 0, 0, 0);
        aM[h] = MFMA16(ahi[h][ks], bl, aM[h], 0, 0, 0);
        aK[h] = MFMA16(mhi[h][ks], bh, aK[h], 0, 0, 0);
        aK[h] = MFMA16(mlo[h][ks], bh, aK[h], 0, 0, 0);
        aK[h] = MFMA16(mhi[h][ks], bl, aK[h], 0, 0, 0);
      }
    }
    // D frag: col = lane&15, row = (lane>>4)*4 + r (per 16-row half)
    const int col = nt * 16 + (lane & 15);
    const float bc = bi[col];
    const float w0 = wb[col * 2 + 0], w1 = wb[col * 2 + 1];
    const float v0 = Wo[col * 2 + 0], v1 = Wo[col * 2 + 1];
    #pragma unroll
    for (int h = 0; h < 2; ++h) {
      #pragma unroll
      for (int r = 0; r < 4; ++r) {
        float a = aM[h][r] + bc; a = a > 0.f ? a : NEG_SLOPE * a;
        s0[h][r] = fmaf(a, w0, s0[h][r]); s1[h][r] = fmaf(a, w1, s1[h][r]);
        float m = aK[h][r] + bc; m = m > 0.f ? m : NEG_SLOPE * m;
        t0[h][r] = fmaf(m, v0, t0[h][r]); t1[h][r] = fmaf(m, v1, t1[h][r]);
      }
    }
  }

  #pragma unroll
  for (int o = 1; o < 16; o <<= 1) {
    #pragma unroll
    for (int h = 0; h < 2; ++h) {
      #pragma unroll
      for (int r = 0; r < 4; ++r) {
        s0[h][r] += __shfl_xor(s0[h][r], o, 16);
        s1[h][r] += __shfl_xor(s1[h][r], o, 16);
        t0[h][r] += __shfl_xor(t0[h][r], o, 16);
        t1[h][r] += __shfl_xor(t1[h][r], o, 16);
      }
    }
  }
  if ((lane & 15) == 0) {
    float bo0 = bo[0], bo1 = bo[1];
    #pragma unroll
    for (int h = 0; h < 2; ++h) {
      #pragma unroll
      for (int r = 0; r < 4; ++r) {
        int row = base + h * 16 + (lane >> 4) * 4 + r;
        if (row < M) {
          float* qf = (float*)&q[row];
          qf[1] = s0[h][r]; // P0 (unscaled); qf[0]=dis written by k_p2
          qf[2] = s1[h][r]; // P1
          Pm[row * 2 + 0] = t0[h][r] + bo0; // mask logit + b_out, final
          Pm[row * 2 + 1] = t1[h][r] + bo1;
        }
      }
    }
  }
}

// ---------------- gather passes (4 lanes per node, 2x unrolled) ----------------
// q[n] = {dis, P0, P1, -};  T2[n] = dis[n]*(dis[n]*(dis[n]*P[n] + sum dis[s]P[s]) + u)
__global__ __launch_bounds__(256) void k_gather1(
    const int* __restrict__ rp, const int* __restrict__ csr,
    const float4* __restrict__ q, const float* __restrict__ uv,
    float* __restrict__ T2, int N) {
  int t = threadIdx.x;
  int n = blockIdx.x * 64 + (t >> 2);
  int l = t & 3;
  if (n >= N) return;
  int s0 = rp[n], s1 = rp[n + 1];
  float a0 = 0.f, a1 = 0.f;
  int j = s0 + l;
  for (; j + 4 < s1; j += 8) {
    int sa = csr[j], sb = csr[j + 4];
    float4 qa = q[sa], qb = q[sb];
    a0 = fmaf(qa.x, qa.y, a0); a1 = fmaf(qa.x, qa.z, a1);
    a0 = fmaf(qb.x, qb.y, a0); a1 = fmaf(qb.x, qb.z, a1);
  }
  if (j < s1) {
    float4 qa = q[csr[j]];
    a0 = fmaf(qa.x, qa.y, a0); a1 = fmaf(qa.x, qa.z, a1);
  }
  a0 += __shfl_xor(a0, 1, 4); a1 += __shfl_xor(a1, 1, 4);
  a0 += __shfl_xor(a0, 2, 4); a1 += __shfl_xor(a1, 2, 4);
  if (l == 0) {
    float4 qn = q[n];
    float d = qn.x;
    T2[n * 2 + 0] = d * (d * fmaf(d, qn.y, a0) + uv[0]);
    T2[n * 2 + 1] = d * (d * fmaf(d, qn.z, a1) + uv[1]);
  }
}

// out[n] = (dis[n]*(T2[n] + sum T2[s]) + v) * Pm[n]   (Pm already has +b_out)
__global__ __launch_bounds__(256) void k_gather2(
    const int* __restrict__ rp, const int* __restrict__ csr,
    const float* __restrict__ T2, const float4* __restrict__ q,
    const float* __restrict__ uv, const float* __restrict__ Pm,
    float* __restrict__ out, int N) {
  int t = threadIdx.x;
  int n = blockIdx.x * 64 + (t >> 2);
  int l = t & 3;
  if (n >= N) return;
  int s0 = rp[n], s1 = rp[n + 1];
  float a0 = 0.f, a1 = 0.f;
  int j = s0 + l;
  for (; j + 4 < s1; j += 8) {
    int sa = csr[j], sb = csr[j + 4];
    float2 va = *(const float2*)&T2[sa * 2];
    float2 vb = *(const float2*)&T2[sb * 2];
    a0 += va.x + vb.x; a1 += va.y + vb.y;
  }
  if (j < s1) {
    float2 va = *(const float2*)&T2[csr[j] * 2];
    a0 += va.x; a1 += va.y;
  }
  a0 += __shfl_xor(a0, 1, 4); a1 += __shfl_xor(a1, 1, 4);
  a0 += __shfl_xor(a0, 2, 4); a1 += __shfl_xor(a1, 2, 4);
  if (l == 0) {
    float d = q[n].x;
    float2 tv = *(const float2*)&T2[n * 2];
    float z0 = d * (tv.x + a0) + uv[2];
    float z1 = d * (tv.y + a1) + uv[3];
    out[n * 2 + 0] = z0 * Pm[n * 2 + 0];
    out[n * 2 + 1] = z1 * Pm[n * 2 + 1];
  }
}

extern "C" void kernel_launch(void* const* d_in, const int* in_sizes, int n_in,
                              void* d_out, int out_size, void* d_ws, size_t ws_size,
                              hipStream_t stream) {
  const float* mf  = (const float*)d_in[0];
  const float* fe  = (const float*)d_in[1];
  const int*   ei  = (const int*)d_in[2];
  const float* Win = (const float*)d_in[4];
  const float* bin = (const float*)d_in[5];
  const float* Wg1 = (const float*)d_in[6];
  const float* bg1 = (const float*)d_in[7];
  const float* Wg2 = (const float*)d_in[8];
  const float* bg2 = (const float*)d_in[9];
  const float* Wo  = (const float*)d_in[10];
  const float* bo  = (const float*)d_in[11];
  float* out = (float*)d_out;

  const int ED = 128;
  const int N = in_sizes[0] / ED;  // 50000
  const int E = in_sizes[3];       // 800000
  const int* src = ei;
  const int* dst = ei + E;

  char* ws = (char*)d_ws;
  size_t off = 0;
  auto carve = [&](size_t bytes) {
    char* p = ws + off;
    off += (bytes + 255) & ~(size_t)255;
    return p;
  };
  int*      cur    = (int*)carve(256 * 4);
  unsigned* packed = (unsigned*)carve((size_t)256 * BSTRIDE * 4); // 8 MB
  int*      csr    = (int*)carve((size_t)E * 4);
  int*      rp     = (int*)carve((size_t)(N + 1) * 4);
  float4*   q      = (float4*)carve((size_t)N * 16);   // {dis, P0, P1, -}
  float*    T2     = (float*)carve((size_t)N * 2 * 4);
  float*    Pm     = (float*)carve((size_t)N * 2 * 4);
  float*    wb     = (float*)carve((size_t)HD * 2 * 4);
  float*    uv     = (float*)carve(4 * 4);
  u16x8*    Wf     = (u16x8*)carve((size_t)128 * 64 * 16); // 128 KB
  (void)ws_size; (void)n_in; (void)out_size;

  const int NB  = (E + CHUNK - 1) / CHUNK;  // 196 scatter blocks
  const int NP2 = (N + 255) / 256;          // 196 buckets
  const int Gg  = (N + 255) / 256;          // 196 GEMM blocks (256 rows each)
  const int Gt  = (N + 63) / 64;            // 782 gather blocks

  k_prep<<<34, 256, 0, stream>>>(Win, Wf, Wg1, Wg2, Wo, bg1, bg2, bo, wb, uv, cur);
  k_scatter<<<NB, 256, 0, stream>>>(src, dst, cur, packed, E);
  k_p2<<<NP2, 256, 0, stream>>>(packed, cur, rp, q, csr, N);
  k_gemm<<<Gg, 512, 0, stream>>>(mf, fe, Wf, bin, wb, Wo, bo, q, Pm, N);
  k_gather1<<<Gt, 256, 0, stream>>>(rp, csr, q, uv, T2, N);
  k_gather2<<<Gt, 256, 0, stream>>>(rp, csr, T2, q, uv, Pm, out, N);
}

// Round 11
// 89.540 us; speedup vs baseline: 1.1263x; 1.1263x over previous
//
#include <hip/hip_runtime.h>

// GCN forward: algebraic collapse + high-occupancy split-bf16 MFMA GEMM
// (16 rows/wave, 782 blocks, Wf staged in 4x32KB LDS chunks, epi consts in LDS)
// overlapped with per-bucket sort role-blocks; bucket-sort CSR build; MLP-4 gathers.
// 5 launches:
//   k_prep    : Wf split + Wbig/u/v consts + zero(cur)
//   k_scatter : LDS hist -> reserve -> LDS-sort -> coalesced bucket write
//   k_main    : [0,Gg) merged main+mask GEMM ; [Gg,Gg+NP2) bucket sort -> rp/dis/csr
//   k_gather1 : T2 = dis*(dis*(agg_dis(P)) + u)
//   k_gather2 : out = (dis*agg(T2) + v) * Pm
// Math:  Z = Â(Â(X1@Wbig) + 1⊗u) + 1⊗v,  Â = D^-1/2 (A+I) D^-1/2
//        out = Z * (lrelu((F-MF)@W_in+b_in)@W_out + b_out)

#define NEG_SLOPE 0.01f
constexpr int HD = 256;
constexpr int CHUNK = 4096;   // edges per scatter block (196 blocks)
constexpr int BSTRIDE = 8192; // packed bucket capacity (expected ~4082)

typedef __bf16 bf16x8 __attribute__((ext_vector_type(8)));
typedef unsigned short u16x8 __attribute__((ext_vector_type(8)));
typedef float f32x4 __attribute__((ext_vector_type(4)));

#define MFMA16 __builtin_amdgcn_mfma_f32_16x16x32_bf16

// split fp32 -> bf16 hi (truncate) + bf16 lo (RNE of remainder)
__device__ inline void split1(float v, unsigned short& h, unsigned short& l) {
  unsigned u = __float_as_uint(v);
  unsigned hb = u & 0xFFFF0000u;
  float lf = v - __uint_as_float(hb);
  unsigned ul = __float_as_uint(lf);
  h = (unsigned short)(hb >> 16);
  l = (unsigned short)((ul + 0x7FFFu + ((ul >> 16) & 1u)) >> 16);
}

// ---------------- prep: W-split + consts + zero(cur) ----------------
__global__ __launch_bounds__(256) void k_prep(
    const float* __restrict__ Win, u16x8* __restrict__ Wf,
    const float* __restrict__ Wg1, const float* __restrict__ Wg2,
    const float* __restrict__ Wo, const float* __restrict__ bg1,
    const float* __restrict__ bg2, const float* __restrict__ bo,
    float* __restrict__ wb, float* __restrict__ uv, int* __restrict__ cur) {
  __shared__ float wt[256][2];
  const int bid = blockIdx.x, tid = threadIdx.x;
  if (bid < 32) {
    // fragment f = nt*8 + ks*2 + hl; lane's 8 elems:
    //   Win[ks*32 + (lane>>4)*8 + j][nt*16 + (lane&15)]
    int f = bid * 4 + (tid >> 6);
    int lane = tid & 63;
    int nt = f >> 3, ks = (f >> 1) & 3, hl = f & 1;
    int n = nt * 16 + (lane & 15);
    int k0 = ks * 32 + (lane >> 4) * 8;
    u16x8 outv;
    #pragma unroll
    for (int j = 0; j < 8; ++j) {
      unsigned short h, l;
      split1(Win[(size_t)(k0 + j) * HD + n], h, l);
      outv[j] = hl ? l : h;
    }
    Wf[f * 64 + lane] = outv;
  } else if (bid == 32) {
    int r = tid;
    float s0 = 0.f, s1 = 0.f;
    for (int k = 0; k < 256; ++k) {
      float w = Wg2[r * 256 + k];
      s0 = fmaf(w, Wo[k * 2 + 0], s0);
      s1 = fmaf(w, Wo[k * 2 + 1], s1);
    }
    wt[r][0] = s0; wt[r][1] = s1;
    __syncthreads();
    float b0 = 0.f, b1 = 0.f;
    for (int k = 0; k < 256; ++k) {
      float w = Wg1[r * 256 + k];
      b0 = fmaf(w, wt[k][0], b0);
      b1 = fmaf(w, wt[k][1], b1);
    }
    wb[r * 2 + 0] = b0; wb[r * 2 + 1] = b1;
    if (r < 2) {
      float u = 0.f, v = 0.f;
      for (int k = 0; k < 256; ++k) {
        u = fmaf(bg1[k], wt[k][r], u);
        v = fmaf(bg2[k], Wo[k * 2 + r], v);
      }
      uv[r] = u;             // u[c]
      uv[2 + r] = v + bo[r]; // v[c]
    }
  } else {
    cur[tid] = 0;
  }
}

// ---------------- scatter: LDS hist+sort, coalesced per-bin global writes -------
__global__ __launch_bounds__(256) void k_scatter(
    const int* __restrict__ src, const int* __restrict__ dst,
    int* __restrict__ cur, unsigned* __restrict__ packed, int E) {
  __shared__ int bins[256], lstart[256], gbase[256], lcur[256];
  __shared__ int wsum[4];
  __shared__ unsigned sbuf[CHUNK]; // 16 KB
  const int t = threadIdx.x, b = blockIdx.x;
  const int lane = t & 63, wid = t >> 6;
  bins[t] = 0;
  __syncthreads();
  const int e0 = b * CHUNK, e1 = min(e0 + CHUNK, E), m = e1 - e0;
  for (int e = e0 + t; e < e1; e += 256)
    atomicAdd(&bins[dst[e] >> 8], 1);
  __syncthreads();
  {
    int v = bins[t], incl = v;
    #pragma unroll
    for (int o = 1; o < 64; o <<= 1) {
      int tmp = __shfl_up(incl, o, 64);
      if (lane >= o) incl += tmp;
    }
    if (lane == 63) wsum[wid] = incl;
    __syncthreads();
    int woff = 0;
    for (int w = 0; w < wid; ++w) woff += wsum[w];
    int st = woff + incl - v;
    lstart[t] = st;
    lcur[t] = st;
    gbase[t] = v ? atomicAdd(&cur[t], v) : 0;
  }
  __syncthreads();
  for (int e = e0 + t; e < e1; e += 256) {
    int d = dst[e], s = src[e];
    int slot = atomicAdd(&lcur[d >> 8], 1);
    sbuf[slot] = ((unsigned)d << 16) | (unsigned)s;
  }
  __syncthreads();
  for (int i = t; i < m; i += 256) {
    unsigned pv = sbuf[i];
    int bin = pv >> 24;
    packed[(size_t)bin * BSTRIDE + gbase[bin] + (i - lstart[bin])] = pv;
  }
}

// ---------------- main: GEMM role [0,Gg) + bucket-sort role [Gg,Gg+NP2) ---------
__global__ __launch_bounds__(256, 3) void k_main(
    const float* __restrict__ mf, const float* __restrict__ fe,
    const u16x8* __restrict__ Wf, const float* __restrict__ bi,
    const float* __restrict__ wb, const float* __restrict__ Wo,
    const float* __restrict__ bo, float4* __restrict__ q, float* __restrict__ Pm,
    const unsigned* __restrict__ packed, const int* __restrict__ cur,
    int* __restrict__ rp, int* __restrict__ csr, int N, int Gg) {
  __shared__ __align__(16) char smem[38912];
  const int tid = threadIdx.x;
  const int lane = tid & 63, wid = tid >> 6;

  if ((int)blockIdx.x < Gg) {
    // ---- GEMM role: 4 waves x 16 rows = 64 rows/block ----
    u16x8*  sB  = (u16x8*)smem;             // 32 KB: 4 nt-tiles of B frags
    float4* sE1 = (float4*)(smem + 32768);  // 4 KB: {bi, wb0, wb1, -} per col
    float2* sE2 = (float2*)(smem + 36864);  // 2 KB: {wo0, wo1} per col
    sE1[tid] = make_float4(bi[tid], wb[2 * tid], wb[2 * tid + 1], 0.f);
    sE2[tid] = make_float2(Wo[2 * tid], Wo[2 * tid + 1]);

    const int base = blockIdx.x * 64 + wid * 16;
    int arow = base + (lane & 15);
    if (arow >= N) arow = N - 1;
    const int kb = (lane >> 4) * 8;
    const float* ap = mf + (size_t)arow * 128 + kb;
    const float* fp = fe + (size_t)arow * 128 + kb;

    // A fragments: main = MF, mask = FE - MF, hi/lo split each
    bf16x8 ahi[4], alo[4], mhi[4], mlo[4];
    #pragma unroll
    for (int ks = 0; ks < 4; ++ks) {
      float x[8], y[8];
      *(float4*)&x[0] = *(const float4*)(ap + ks * 32);
      *(float4*)&x[4] = *(const float4*)(ap + ks * 32 + 4);
      *(float4*)&y[0] = *(const float4*)(fp + ks * 32);
      *(float4*)&y[4] = *(const float4*)(fp + ks * 32 + 4);
      u16x8 hA, lA, hM, lM;
      #pragma unroll
      for (int j = 0; j < 8; ++j) {
        unsigned short hh, ll;
        split1(x[j], hh, ll);        hA[j] = hh; lA[j] = ll;
        split1(y[j] - x[j], hh, ll); hM[j] = hh; lM[j] = ll;
      }
      ahi[ks] = __builtin_bit_cast(bf16x8, hA);
      alo[ks] = __builtin_bit_cast(bf16x8, lA);
      mhi[ks] = __builtin_bit_cast(bf16x8, hM);
      mlo[ks] = __builtin_bit_cast(bf16x8, lM);
    }

    float s0[4] = {}, s1[4] = {}, t0[4] = {}, t1[4] = {};
    #pragma unroll 1
    for (int g = 0; g < 4; ++g) {
      __syncthreads(); // previous chunk fully consumed (also covers sE1/sE2 write)
      #pragma unroll
      for (int i = 0; i < 8; ++i)
        sB[tid + i * 256] = Wf[g * 2048 + tid + i * 256]; // 32 KB chunk
      __syncthreads();
      #pragma unroll
      for (int ntl = 0; ntl < 4; ++ntl) {
        const int nt = g * 4 + ntl;
        f32x4 aM = {0, 0, 0, 0}, aK = {0, 0, 0, 0};
        #pragma unroll
        for (int ks = 0; ks < 4; ++ks) {
          bf16x8 bh = __builtin_bit_cast(bf16x8, sB[(ntl * 8 + ks * 2 + 0) * 64 + lane]);
          bf16x8 bl = __builtin_bit_cast(bf16x8, sB[(ntl * 8 + ks * 2 + 1) * 64 + lane]);
          aM = MFMA16(ahi[ks], bh, aM, 0, 0, 0);
          aM = MFMA16(alo[ks], bh, aM, 0, 0, 0);
          aM = MFMA16(ahi[ks], bl, aM, 0, 0, 0);
          aK = MFMA16(mhi[ks], bh, aK, 0, 0, 0);
          aK = MFMA16(mlo[ks], bh, aK, 0, 0, 0);
          aK = MFMA16(mhi[ks], bl, aK, 0, 0, 0);
        }
        // D frag: col = lane&15, row = (lane>>4)*4 + r
        const int col = nt * 16 + (lane & 15);
        const float4 e1 = sE1[col];
        const float2 e2 = sE2[col];
        #pragma unroll
        for (int r = 0; r < 4; ++r) {
          float a = aM[r] + e1.x; a = a > 0.f ? a : NEG_SLOPE * a;
          s0[r] = fmaf(a, e1.y, s0[r]); s1[r] = fmaf(a, e1.z, s1[r]);
          float m = aK[r] + e1.x; m = m > 0.f ? m : NEG_SLOPE * m;
          t0[r] = fmaf(m, e2.x, t0[r]); t1[r] = fmaf(m, e2.y, t1[r]);
        }
      }
    }

    #pragma unroll
    for (int o = 1; o < 16; o <<= 1) {
      #pragma unroll
      for (int r = 0; r < 4; ++r) {
        s0[r] += __shfl_xor(s0[r], o, 16); s1[r] += __shfl_xor(s1[r], o, 16);
        t0[r] += __shfl_xor(t0[r], o, 16); t1[r] += __shfl_xor(t1[r], o, 16);
      }
    }
    if ((lane & 15) == 0) {
      float bo0 = bo[0], bo1 = bo[1];
      #pragma unroll
      for (int r = 0; r < 4; ++r) {
        int row = base + (lane >> 4) * 4 + r;
        if (row < N) {
          float* qf = (float*)&q[row];
          qf[1] = s0[r]; // P0 (unscaled); qf[0]=dis from sort role
          qf[2] = s1[r]; // P1
          Pm[row * 2 + 0] = t0[r] + bo0;
          Pm[row * 2 + 1] = t1[r] + bo1;
        }
      }
    }
    return;
  }

  // ---- sort role: per-bucket sort -> rp/dis/csr ----
  int* cnt = (int*)smem;                                   // 1 KB
  int* sc  = (int*)(smem + 1024);                          // 1 KB
  int* wsum = (int*)(smem + 2048);                         // 16 B
  unsigned short* sbuf = (unsigned short*)(smem + 2064);   // 16 KB
  const int t = tid;
  const int B = blockIdx.x - Gg;
  // global bucket base = exclusive scan of cur at index B
  int tot = cur[t], incl = tot;
  #pragma unroll
  for (int o = 1; o < 64; o <<= 1) {
    int tmp = __shfl_up(incl, o, 64);
    if (lane >= o) incl += tmp;
  }
  if (lane == 63) wsum[wid] = incl;
  __syncthreads();
  int woff = 0;
  for (int w = 0; w < wid; ++w) woff += wsum[w];
  sc[t] = woff + incl - tot;
  __syncthreads();
  const int base = sc[B];
  const int ecnt = cur[B];
  const unsigned* pk = packed + (size_t)B * BSTRIDE;
  cnt[t] = 0;
  __syncthreads();
  for (int i = t; i < ecnt; i += 256)
    atomicAdd(&cnt[(pk[i] >> 16) & 0xFF], 1);
  __syncthreads();
  int v = cnt[t];
  incl = v;
  #pragma unroll
  for (int o = 1; o < 64; o <<= 1) {
    int tmp = __shfl_up(incl, o, 64);
    if (lane >= o) incl += tmp;
  }
  if (lane == 63) wsum[wid] = incl;
  __syncthreads();
  woff = 0;
  for (int w = 0; w < wid; ++w) woff += wsum[w];
  const int off = woff + incl - v;
  const int node = B * 256 + t;
  if (node < N) {
    rp[node] = base + off;
    ((float*)&q[node])[0] = rsqrtf((float)(v + 1)); // dis (+1 self-loop)
  } else if (node == N) {
    rp[N] = base + off; // == E
  }
  __syncthreads();
  cnt[t] = off; // LDS cursor
  __syncthreads();
  for (int i = t; i < ecnt; i += 256) {
    unsigned pv = pk[i];
    int slot = atomicAdd(&cnt[(pv >> 16) & 0xFF], 1);
    sbuf[slot] = (unsigned short)(pv & 0xFFFFu);
  }
  __syncthreads();
  for (int i = t; i < ecnt; i += 256)
    csr[base + i] = (int)sbuf[i];
}

// ---------------- gather passes (4 lanes/node, 4-deep MLP) ----------------
// q[n] = {dis, P0, P1, -};  T2[n] = dis[n]*(dis[n]*(dis[n]*P[n] + sum dis[s]P[s]) + u)
__global__ __launch_bounds__(256) void k_gather1(
    const int* __restrict__ rp, const int* __restrict__ csr,
    const float4* __restrict__ q, const float* __restrict__ uv,
    float* __restrict__ T2, int N) {
  int t = threadIdx.x;
  int n = blockIdx.x * 64 + (t >> 2);
  int l = t & 3;
  if (n >= N) return;
  int s0 = rp[n], s1 = rp[n + 1];
  float a0 = 0.f, a1 = 0.f;
  int j = s0 + l;
  for (; j + 12 < s1; j += 16) {
    int i0 = csr[j], i1 = csr[j + 4], i2 = csr[j + 8], i3 = csr[j + 12];
    float4 q0 = q[i0], q1 = q[i1], q2 = q[i2], q3 = q[i3];
    a0 = fmaf(q0.x, q0.y, a0); a1 = fmaf(q0.x, q0.z, a1);
    a0 = fmaf(q1.x, q1.y, a0); a1 = fmaf(q1.x, q1.z, a1);
    a0 = fmaf(q2.x, q2.y, a0); a1 = fmaf(q2.x, q2.z, a1);
    a0 = fmaf(q3.x, q3.y, a0); a1 = fmaf(q3.x, q3.z, a1);
  }
  for (; j < s1; j += 4) {
    float4 qa = q[csr[j]];
    a0 = fmaf(qa.x, qa.y, a0); a1 = fmaf(qa.x, qa.z, a1);
  }
  a0 += __shfl_xor(a0, 1, 4); a1 += __shfl_xor(a1, 1, 4);
  a0 += __shfl_xor(a0, 2, 4); a1 += __shfl_xor(a1, 2, 4);
  if (l == 0) {
    float4 qn = q[n];
    float d = qn.x;
    T2[n * 2 + 0] = d * (d * fmaf(d, qn.y, a0) + uv[0]);
    T2[n * 2 + 1] = d * (d * fmaf(d, qn.z, a1) + uv[1]);
  }
}

// out[n] = (dis[n]*(T2[n] + sum T2[s]) + v) * Pm[n]   (Pm already has +b_out)
__global__ __launch_bounds__(256) void k_gather2(
    const int* __restrict__ rp, const int* __restrict__ csr,
    const float* __restrict__ T2, const float4* __restrict__ q,
    const float* __restrict__ uv, const float* __restrict__ Pm,
    float* __restrict__ out, int N) {
  int t = threadIdx.x;
  int n = blockIdx.x * 64 + (t >> 2);
  int l = t & 3;
  if (n >= N) return;
  int s0 = rp[n], s1 = rp[n + 1];
  float a0 = 0.f, a1 = 0.f;
  int j = s0 + l;
  for (; j + 12 < s1; j += 16) {
    int i0 = csr[j], i1 = csr[j + 4], i2 = csr[j + 8], i3 = csr[j + 12];
    float2 v0 = *(const float2*)&T2[i0 * 2];
    float2 v1 = *(const float2*)&T2[i1 * 2];
    float2 v2 = *(const float2*)&T2[i2 * 2];
    float2 v3 = *(const float2*)&T2[i3 * 2];
    a0 += (v0.x + v1.x) + (v2.x + v3.x);
    a1 += (v0.y + v1.y) + (v2.y + v3.y);
  }
  for (; j < s1; j += 4) {
    float2 va = *(const float2*)&T2[csr[j] * 2];
    a0 += va.x; a1 += va.y;
  }
  a0 += __shfl_xor(a0, 1, 4); a1 += __shfl_xor(a1, 1, 4);
  a0 += __shfl_xor(a0, 2, 4); a1 += __shfl_xor(a1, 2, 4);
  if (l == 0) {
    float d = q[n].x;
    float2 tv = *(const float2*)&T2[n * 2];
    float z0 = d * (tv.x + a0) + uv[2];
    float z1 = d * (tv.y + a1) + uv[3];
    out[n * 2 + 0] = z0 * Pm[n * 2 + 0];
    out[n * 2 + 1] = z1 * Pm[n * 2 + 1];
  }
}

extern "C" void kernel_launch(void* const* d_in, const int* in_sizes, int n_in,
                              void* d_out, int out_size, void* d_ws, size_t ws_size,
                              hipStream_t stream) {
  const float* mf  = (const float*)d_in[0];
  const float* fe  = (const float*)d_in[1];
  const int*   ei  = (const int*)d_in[2];
  const float* Win = (const float*)d_in[4];
  const float* bin = (const float*)d_in[5];
  const float* Wg1 = (const float*)d_in[6];
  const float* bg1 = (const float*)d_in[7];
  const float* Wg2 = (const float*)d_in[8];
  const float* bg2 = (const float*)d_in[9];
  const float* Wo  = (const float*)d_in[10];
  const float* bo  = (const float*)d_in[11];
  float* out = (float*)d_out;

  const int ED = 128;
  const int N = in_sizes[0] / ED;  // 50000
  const int E = in_sizes[3];       // 800000
  const int* src = ei;
  const int* dst = ei + E;

  char* ws = (char*)d_ws;
  size_t off = 0;
  auto carve = [&](size_t bytes) {
    char* p = ws + off;
    off += (bytes + 255) & ~(size_t)255;
    return p;
  };
  int*      cur    = (int*)carve(256 * 4);
  unsigned* packed = (unsigned*)carve((size_t)256 * BSTRIDE * 4); // 8 MB
  int*      csr    = (int*)carve((size_t)E * 4);
  int*      rp     = (int*)carve((size_t)(N + 1) * 4);
  float4*   q      = (float4*)carve((size_t)N * 16);   // {dis, P0, P1, -}
  float*    T2     = (float*)carve((size_t)N * 2 * 4);
  float*    Pm     = (float*)carve((size_t)N * 2 * 4);
  float*    wb     = (float*)carve((size_t)HD * 2 * 4);
  float*    uv     = (float*)carve(4 * 4);
  u16x8*    Wf     = (u16x8*)carve((size_t)128 * 64 * 16); // 128 KB
  (void)ws_size; (void)n_in; (void)out_size;

  const int NB  = (E + CHUNK - 1) / CHUNK;  // 196 scatter blocks
  const int NP2 = (N + 255) / 256;          // 196 buckets
  const int Gg  = (N + 63) / 64;            // 782 GEMM role blocks
  const int Gt  = (N + 63) / 64;            // 782 gather blocks

  k_prep<<<34, 256, 0, stream>>>(Win, Wf, Wg1, Wg2, Wo, bg1, bg2, bo, wb, uv, cur);
  k_scatter<<<NB, 256, 0, stream>>>(src, dst, cur, packed, E);
  k_main<<<Gg + NP2, 256, 0, stream>>>(mf, fe, Wf, bin, wb, Wo, bo, q, Pm,
                                       packed, cur, rp, csr, N, Gg);
  k_gather1<<<Gt, 256, 0, stream>>>(rp, csr, q, uv, T2, N);
  k_gather2<<<Gt, 256, 0, stream>>>(rp, csr, T2, q, uv, Pm, out, N);
}

// Round 12
// 88.923 us; speedup vs baseline: 1.1341x; 1.0069x over previous
//
#include <hip/hip_runtime.h>

// GCN forward: algebraic collapse + split-bf16 MFMA GEMM with COALESCED A-staging
// (flat float4 loads -> split -> fragment-ordered bf16 LDS with XOR swizzle; A-frags
// read once into regs; B reg-dbuf from L2) overlapped with bucket-sort role-blocks.
// 5 launches:
//   k_prep    : Wf split + Wbig/u/v consts + zero(cur)
//   k_scatter : LDS hist -> reserve -> LDS-sort -> coalesced bucket write
//   k_main    : [0,Gg) merged main+mask GEMM ; [Gg,Gg+NP2) bucket sort -> rp/dis/csr
//   k_gather1 : T2 = dis*(dis*(agg_dis(P)) + u)
//   k_gather2 : out = (dis*agg(T2) + v) * Pm
// Math:  Z = Â(Â(X1@Wbig) + 1⊗u) + 1⊗v,  Â = D^-1/2 (A+I) D^-1/2
//        out = Z * (lrelu((F-MF)@W_in+b_in)@W_out + b_out)
// R11 theory: R6-R10 GEMMs all pinned at ~41us by the strided per-lane A-read
// pattern (~1.2 TB/s effective). Fix = coalesced panel staging via LDS.

#define NEG_SLOPE 0.01f
constexpr int HD = 256;
constexpr int CHUNK = 4096;   // edges per scatter block (196 blocks)
constexpr int BSTRIDE = 8192; // packed bucket capacity (expected ~4082)

typedef __bf16 bf16x8 __attribute__((ext_vector_type(8)));
typedef unsigned short u16x8 __attribute__((ext_vector_type(8)));
typedef float f32x4 __attribute__((ext_vector_type(4)));

#define MFMA16 __builtin_amdgcn_mfma_f32_16x16x32_bf16

// split fp32 -> bf16 hi (truncate) + bf16 lo (RNE of remainder)
__device__ inline void split1(float v, unsigned short& h, unsigned short& l) {
  unsigned u = __float_as_uint(v);
  unsigned hb = u & 0xFFFF0000u;
  float lf = v - __uint_as_float(hb);
  unsigned ul = __float_as_uint(lf);
  h = (unsigned short)(hb >> 16);
  l = (unsigned short)((ul + 0x7FFFu + ((ul >> 16) & 1u)) >> 16);
}

__device__ inline uint2 pack4(const unsigned short* s) {
  return make_uint2((unsigned)s[0] | ((unsigned)s[1] << 16),
                    (unsigned)s[2] | ((unsigned)s[3] << 16));
}

// ---------------- prep: W-split + consts + zero(cur) ----------------
__global__ __launch_bounds__(256) void k_prep(
    const float* __restrict__ Win, u16x8* __restrict__ Wf,
    const float* __restrict__ Wg1, const float* __restrict__ Wg2,
    const float* __restrict__ Wo, const float* __restrict__ bg1,
    const float* __restrict__ bg2, const float* __restrict__ bo,
    float* __restrict__ wb, float* __restrict__ uv, int* __restrict__ cur) {
  __shared__ float wt[256][2];
  const int bid = blockIdx.x, tid = threadIdx.x;
  if (bid < 32) {
    // fragment f = nt*8 + ks*2 + hl; lane's 8 elems:
    //   Win[ks*32 + (lane>>4)*8 + j][nt*16 + (lane&15)]
    int f = bid * 4 + (tid >> 6);
    int lane = tid & 63;
    int nt = f >> 3, ks = (f >> 1) & 3, hl = f & 1;
    int n = nt * 16 + (lane & 15);
    int k0 = ks * 32 + (lane >> 4) * 8;
    u16x8 outv;
    #pragma unroll
    for (int j = 0; j < 8; ++j) {
      unsigned short h, l;
      split1(Win[(size_t)(k0 + j) * HD + n], h, l);
      outv[j] = hl ? l : h;
    }
    Wf[f * 64 + lane] = outv;
  } else if (bid == 32) {
    int r = tid;
    float s0 = 0.f, s1 = 0.f;
    for (int k = 0; k < 256; ++k) {
      float w = Wg2[r * 256 + k];
      s0 = fmaf(w, Wo[k * 2 + 0], s0);
      s1 = fmaf(w, Wo[k * 2 + 1], s1);
    }
    wt[r][0] = s0; wt[r][1] = s1;
    __syncthreads();
    float b0 = 0.f, b1 = 0.f;
    for (int k = 0; k < 256; ++k) {
      float w = Wg1[r * 256 + k];
      b0 = fmaf(w, wt[k][0], b0);
      b1 = fmaf(w, wt[k][1], b1);
    }
    wb[r * 2 + 0] = b0; wb[r * 2 + 1] = b1;
    if (r < 2) {
      float u = 0.f, v = 0.f;
      for (int k = 0; k < 256; ++k) {
        u = fmaf(bg1[k], wt[k][r], u);
        v = fmaf(bg2[k], Wo[k * 2 + r], v);
      }
      uv[r] = u;             // u[c]
      uv[2 + r] = v + bo[r]; // v[c]
    }
  } else {
    cur[tid] = 0;
  }
}

// ---------------- scatter: LDS hist+sort, coalesced per-bin global writes -------
__global__ __launch_bounds__(256) void k_scatter(
    const int* __restrict__ src, const int* __restrict__ dst,
    int* __restrict__ cur, unsigned* __restrict__ packed, int E) {
  __shared__ int bins[256], lstart[256], gbase[256], lcur[256];
  __shared__ int wsum[4];
  __shared__ unsigned sbuf[CHUNK]; // 16 KB
  const int t = threadIdx.x, b = blockIdx.x;
  const int lane = t & 63, wid = t >> 6;
  bins[t] = 0;
  __syncthreads();
  const int e0 = b * CHUNK, e1 = min(e0 + CHUNK, E), m = e1 - e0;
  for (int e = e0 + t; e < e1; e += 256)
    atomicAdd(&bins[dst[e] >> 8], 1);
  __syncthreads();
  {
    int v = bins[t], incl = v;
    #pragma unroll
    for (int o = 1; o < 64; o <<= 1) {
      int tmp = __shfl_up(incl, o, 64);
      if (lane >= o) incl += tmp;
    }
    if (lane == 63) wsum[wid] = incl;
    __syncthreads();
    int woff = 0;
    for (int w = 0; w < wid; ++w) woff += wsum[w];
    int st = woff + incl - v;
    lstart[t] = st;
    lcur[t] = st;
    gbase[t] = v ? atomicAdd(&cur[t], v) : 0;
  }
  __syncthreads();
  for (int e = e0 + t; e < e1; e += 256) {
    int d = dst[e], s = src[e];
    int slot = atomicAdd(&lcur[d >> 8], 1);
    sbuf[slot] = ((unsigned)d << 16) | (unsigned)s;
  }
  __syncthreads();
  for (int i = t; i < m; i += 256) {
    unsigned pv = sbuf[i];
    int bin = pv >> 24;
    packed[(size_t)bin * BSTRIDE + gbase[bin] + (i - lstart[bin])] = pv;
  }
}

// ---------------- main: GEMM role [0,Gg) + bucket-sort role [Gg,Gg+NP2) ---------
// LDS (GEMM role): [0,16K) main-hi frags, [16,32K) main-lo, [32,48K) mask-hi,
// [48,64K) mask-lo  -- each [panel][ks][lane][8 bf16], XOR-swizzled;
// [64,68K) sE1 float4[256] {bi,wb0,wb1,-}; [68,70K) sE2 float2[256] {wo0,wo1}.
__global__ __launch_bounds__(256, 2) void k_main(
    const float* __restrict__ mf, const float* __restrict__ fe,
    const u16x8* __restrict__ Wf, const float* __restrict__ bi,
    const float* __restrict__ wb, const float* __restrict__ Wo,
    const float* __restrict__ bo, float4* __restrict__ q, float* __restrict__ Pm,
    const unsigned* __restrict__ packed, const int* __restrict__ cur,
    int* __restrict__ rp, int* __restrict__ csr, int N, int Gg) {
  __shared__ __align__(16) char smem[71680];
  const int tid = threadIdx.x;
  const int lane = tid & 63, wid = tid >> 6;

  if ((int)blockIdx.x < Gg) {
    char* sA = smem;
    float4* sE1 = (float4*)(smem + 65536);
    float2* sE2 = (float2*)(smem + 69632);
    sE1[tid] = make_float4(bi[tid], wb[2 * tid], wb[2 * tid + 1], 0.f);
    sE2[tid] = make_float2(Wo[2 * tid], Wo[2 * tid + 1]);

    // ---- coalesced A staging: 64 rows x 128 f32, both matrices ----
    const int gb = blockIdx.x * 64;
    #pragma unroll
    for (int p = 0; p < 8; ++p) {
      int i = p * 256 + tid;
      int row = i >> 5, c = i & 31; // 32 lanes cover one full 512B row
      int gr = gb + row;
      if (gr >= N) gr = N - 1;
      float4 xm = ((const float4*)mf)[(size_t)gr * 32 + c];
      float4 xf = ((const float4*)fe)[(size_t)gr * 32 + c];
      unsigned short mh[4], ml[4], kh[4], kl[4];
      float xs[4] = {xm.x, xm.y, xm.z, xm.w};
      float ys[4] = {xf.x - xm.x, xf.y - xm.y, xf.z - xm.z, xf.w - xm.w};
      #pragma unroll
      for (int j = 0; j < 4; ++j) {
        split1(xs[j], mh[j], ml[j]);
        split1(ys[j], kh[j], kl[j]);
      }
      int c4 = c * 4;
      int panel = row >> 4, r = row & 15;
      int ks = c4 >> 5, kbg = (c4 >> 3) & 3, j0 = c4 & 7;
      int a = panel * 4096 + ks * 1024 + (kbg * 16 + r) * 16 + j0 * 2;
      a ^= (kbg << 4) ^ ((ks & 1) << 6); // bank swizzle (writer: 16-way -> 2-way)
      *(uint2*)(sA + a)         = pack4(mh);
      *(uint2*)(sA + 16384 + a) = pack4(ml);
      *(uint2*)(sA + 32768 + a) = pack4(kh);
      *(uint2*)(sA + 49152 + a) = pack4(kl);
    }
    __syncthreads();

    // ---- A fragments -> registers (read once, reused for all 16 nt) ----
    bf16x8 Ah[4], Al[4], Kh[4], Kl[4];
    #pragma unroll
    for (int ks = 0; ks < 4; ++ks) {
      int a = wid * 4096 + ks * 1024 + lane * 16;
      a ^= ((lane >> 4) << 4) ^ ((ks & 1) << 6);
      Ah[ks] = *(const bf16x8*)(sA + a);
      Al[ks] = *(const bf16x8*)(sA + 16384 + a);
      Kh[ks] = *(const bf16x8*)(sA + 32768 + a);
      Kl[ks] = *(const bf16x8*)(sA + 49152 + a);
    }

    // ---- nt loop: pure MFMA + B reg-dbuf from L2 ----
    const u16x8* wp = Wf + lane;
    float s0[4] = {}, s1[4] = {}, t0v[4] = {}, t1v[4] = {};
    u16x8 bA[8], bB[8];
    #pragma unroll
    for (int f = 0; f < 8; ++f) bA[f] = wp[f * 64];

    auto COMPUTE = [&](const u16x8* b, int nt) {
      f32x4 aM = {0, 0, 0, 0}, aK = {0, 0, 0, 0};
      #pragma unroll
      for (int ks = 0; ks < 4; ++ks) {
        bf16x8 bh = __builtin_bit_cast(bf16x8, b[ks * 2 + 0]);
        bf16x8 bl = __builtin_bit_cast(bf16x8, b[ks * 2 + 1]);
        aM = MFMA16(Ah[ks], bh, aM, 0, 0, 0);
        aM = MFMA16(Al[ks], bh, aM, 0, 0, 0);
        aM = MFMA16(Ah[ks], bl, aM, 0, 0, 0);
        aK = MFMA16(Kh[ks], bh, aK, 0, 0, 0);
        aK = MFMA16(Kl[ks], bh, aK, 0, 0, 0);
        aK = MFMA16(Kh[ks], bl, aK, 0, 0, 0);
      }
      const int col = nt * 16 + (lane & 15);
      const float4 e1 = sE1[col];
      const float2 e2 = sE2[col];
      #pragma unroll
      for (int r = 0; r < 4; ++r) {
        float a = aM[r] + e1.x; a = a > 0.f ? a : NEG_SLOPE * a;
        s0[r] = fmaf(a, e1.y, s0[r]); s1[r] = fmaf(a, e1.z, s1[r]);
        float m = aK[r] + e1.x; m = m > 0.f ? m : NEG_SLOPE * m;
        t0v[r] = fmaf(m, e2.x, t0v[r]); t1v[r] = fmaf(m, e2.y, t1v[r]);
      }
    };

    #pragma unroll 1
    for (int nt = 0; nt < 16; nt += 2) {
      #pragma unroll
      for (int f = 0; f < 8; ++f) bB[f] = wp[((nt + 1) * 8 + f) * 64];
      COMPUTE(bA, nt);
      if (nt + 2 < 16) {
        #pragma unroll
        for (int f = 0; f < 8; ++f) bA[f] = wp[((nt + 2) * 8 + f) * 64];
      }
      COMPUTE(bB, nt + 1);
    }

    #pragma unroll
    for (int o = 1; o < 16; o <<= 1) {
      #pragma unroll
      for (int r = 0; r < 4; ++r) {
        s0[r] += __shfl_xor(s0[r], o, 16);  s1[r] += __shfl_xor(s1[r], o, 16);
        t0v[r] += __shfl_xor(t0v[r], o, 16); t1v[r] += __shfl_xor(t1v[r], o, 16);
      }
    }
    if ((lane & 15) == 0) {
      float bo0 = bo[0], bo1 = bo[1];
      #pragma unroll
      for (int r = 0; r < 4; ++r) {
        int row = gb + wid * 16 + (lane >> 4) * 4 + r;
        if (row < N) {
          float* qf = (float*)&q[row];
          qf[1] = s0[r]; // P0 (unscaled); qf[0]=dis from sort role
          qf[2] = s1[r]; // P1
          Pm[row * 2 + 0] = t0v[r] + bo0;
          Pm[row * 2 + 1] = t1v[r] + bo1;
        }
      }
    }
    return;
  }

  // ---- sort role: per-bucket sort -> rp/dis/csr ----
  int* cnt = (int*)smem;                                  // 1 KB
  int* sc  = (int*)(smem + 1024);                         // 1 KB
  int* wsum = (int*)(smem + 2048);                        // 16 B
  unsigned short* sbuf = (unsigned short*)(smem + 2064);  // 16 KB
  const int t = tid;
  const int B = blockIdx.x - Gg;
  int tot = cur[t], incl = tot;
  #pragma unroll
  for (int o = 1; o < 64; o <<= 1) {
    int tmp = __shfl_up(incl, o, 64);
    if (lane >= o) incl += tmp;
  }
  if (lane == 63) wsum[wid] = incl;
  __syncthreads();
  int woff = 0;
  for (int w = 0; w < wid; ++w) woff += wsum[w];
  sc[t] = woff + incl - tot;
  __syncthreads();
  const int base = sc[B];
  const int ecnt = cur[B];
  const unsigned* pk = packed + (size_t)B * BSTRIDE;
  cnt[t] = 0;
  __syncthreads();
  for (int i = t; i < ecnt; i += 256)
    atomicAdd(&cnt[(pk[i] >> 16) & 0xFF], 1);
  __syncthreads();
  int v = cnt[t];
  incl = v;
  #pragma unroll
  for (int o = 1; o < 64; o <<= 1) {
    int tmp = __shfl_up(incl, o, 64);
    if (lane >= o) incl += tmp;
  }
  if (lane == 63) wsum[wid] = incl;
  __syncthreads();
  woff = 0;
  for (int w = 0; w < wid; ++w) woff += wsum[w];
  const int off = woff + incl - v;
  const int node = B * 256 + t;
  if (node < N) {
    rp[node] = base + off;
    ((float*)&q[node])[0] = rsqrtf((float)(v + 1)); // dis (+1 self-loop)
  } else if (node == N) {
    rp[N] = base + off; // == E
  }
  __syncthreads();
  cnt[t] = off; // LDS cursor
  __syncthreads();
  for (int i = t; i < ecnt; i += 256) {
    unsigned pv = pk[i];
    int slot = atomicAdd(&cnt[(pv >> 16) & 0xFF], 1);
    sbuf[slot] = (unsigned short)(pv & 0xFFFFu);
  }
  __syncthreads();
  for (int i = t; i < ecnt; i += 256)
    csr[base + i] = (int)sbuf[i];
}

// ---------------- gather passes (4 lanes/node, 4-deep MLP) ----------------
// q[n] = {dis, P0, P1, -};  T2[n] = dis[n]*(dis[n]*(dis[n]*P[n] + sum dis[s]P[s]) + u)
__global__ __launch_bounds__(256) void k_gather1(
    const int* __restrict__ rp, const int* __restrict__ csr,
    const float4* __restrict__ q, const float* __restrict__ uv,
    float* __restrict__ T2, int N) {
  int t = threadIdx.x;
  int n = blockIdx.x * 64 + (t >> 2);
  int l = t & 3;
  if (n >= N) return;
  int s0 = rp[n], s1 = rp[n + 1];
  float a0 = 0.f, a1 = 0.f;
  int j = s0 + l;
  for (; j + 12 < s1; j += 16) {
    int i0 = csr[j], i1 = csr[j + 4], i2 = csr[j + 8], i3 = csr[j + 12];
    float4 q0 = q[i0], q1 = q[i1], q2 = q[i2], q3 = q[i3];
    a0 = fmaf(q0.x, q0.y, a0); a1 = fmaf(q0.x, q0.z, a1);
    a0 = fmaf(q1.x, q1.y, a0); a1 = fmaf(q1.x, q1.z, a1);
    a0 = fmaf(q2.x, q2.y, a0); a1 = fmaf(q2.x, q2.z, a1);
    a0 = fmaf(q3.x, q3.y, a0); a1 = fmaf(q3.x, q3.z, a1);
  }
  for (; j < s1; j += 4) {
    float4 qa = q[csr[j]];
    a0 = fmaf(qa.x, qa.y, a0); a1 = fmaf(qa.x, qa.z, a1);
  }
  a0 += __shfl_xor(a0, 1, 4); a1 += __shfl_xor(a1, 1, 4);
  a0 += __shfl_xor(a0, 2, 4); a1 += __shfl_xor(a1, 2, 4);
  if (l == 0) {
    float4 qn = q[n];
    float d = qn.x;
    T2[n * 2 + 0] = d * (d * fmaf(d, qn.y, a0) + uv[0]);
    T2[n * 2 + 1] = d * (d * fmaf(d, qn.z, a1) + uv[1]);
  }
}

// out[n] = (dis[n]*(T2[n] + sum T2[s]) + v) * Pm[n]   (Pm already has +b_out)
__global__ __launch_bounds__(256) void k_gather2(
    const int* __restrict__ rp, const int* __restrict__ csr,
    const float* __restrict__ T2, const float4* __restrict__ q,
    const float* __restrict__ uv, const float* __restrict__ Pm,
    float* __restrict__ out, int N) {
  int t = threadIdx.x;
  int n = blockIdx.x * 64 + (t >> 2);
  int l = t & 3;
  if (n >= N) return;
  int s0 = rp[n], s1 = rp[n + 1];
  float a0 = 0.f, a1 = 0.f;
  int j = s0 + l;
  for (; j + 12 < s1; j += 16) {
    int i0 = csr[j], i1 = csr[j + 4], i2 = csr[j + 8], i3 = csr[j + 12];
    float2 v0 = *(const float2*)&T2[i0 * 2];
    float2 v1 = *(const float2*)&T2[i1 * 2];
    float2 v2 = *(const float2*)&T2[i2 * 2];
    float2 v3 = *(const float2*)&T2[i3 * 2];
    a0 += (v0.x + v1.x) + (v2.x + v3.x);
    a1 += (v0.y + v1.y) + (v2.y + v3.y);
  }
  for (; j < s1; j += 4) {
    float2 va = *(const float2*)&T2[csr[j] * 2];
    a0 += va.x; a1 += va.y;
  }
  a0 += __shfl_xor(a0, 1, 4); a1 += __shfl_xor(a1, 1, 4);
  a0 += __shfl_xor(a0, 2, 4); a1 += __shfl_xor(a1, 2, 4);
  if (l == 0) {
    float d = q[n].x;
    float2 tv = *(const float2*)&T2[n * 2];
    float z0 = d * (tv.x + a0) + uv[2];
    float z1 = d * (tv.y + a1) + uv[3];
    out[n * 2 + 0] = z0 * Pm[n * 2 + 0];
    out[n * 2 + 1] = z1 * Pm[n * 2 + 1];
  }
}

extern "C" void kernel_launch(void* const* d_in, const int* in_sizes, int n_in,
                              void* d_out, int out_size, void* d_ws, size_t ws_size,
                              hipStream_t stream) {
  const float* mf  = (const float*)d_in[0];
  const float* fe  = (const float*)d_in[1];
  const int*   ei  = (const int*)d_in[2];
  const float* Win = (const float*)d_in[4];
  const float* bin = (const float*)d_in[5];
  const float* Wg1 = (const float*)d_in[6];
  const float* bg1 = (const float*)d_in[7];
  const float* Wg2 = (const float*)d_in[8];
  const float* bg2 = (const float*)d_in[9];
  const float* Wo  = (const float*)d_in[10];
  const float* bo  = (const float*)d_in[11];
  float* out = (float*)d_out;

  const int ED = 128;
  const int N = in_sizes[0] / ED;  // 50000
  const int E = in_sizes[3];       // 800000
  const int* src = ei;
  const int* dst = ei + E;

  char* ws = (char*)d_ws;
  size_t off = 0;
  auto carve = [&](size_t bytes) {
    char* p = ws + off;
    off += (bytes + 255) & ~(size_t)255;
    return p;
  };
  int*      cur    = (int*)carve(256 * 4);
  unsigned* packed = (unsigned*)carve((size_t)256 * BSTRIDE * 4); // 8 MB
  int*      csr    = (int*)carve((size_t)E * 4);
  int*      rp     = (int*)carve((size_t)(N + 1) * 4);
  float4*   q      = (float4*)carve((size_t)N * 16);   // {dis, P0, P1, -}
  float*    T2     = (float*)carve((size_t)N * 2 * 4);
  float*    Pm     = (float*)carve((size_t)N * 2 * 4);
  float*    wb     = (float*)carve((size_t)HD * 2 * 4);
  float*    uv     = (float*)carve(4 * 4);
  u16x8*    Wf     = (u16x8*)carve((size_t)128 * 64 * 16); // 128 KB
  (void)ws_size; (void)n_in; (void)out_size;

  const int NB  = (E + CHUNK - 1) / CHUNK;  // 196 scatter blocks
  const int NP2 = (N + 255) / 256;          // 196 buckets
  const int Gg  = (N + 63) / 64;            // 782 GEMM role blocks
  const int Gt  = (N + 63) / 64;            // 782 gather blocks

  k_prep<<<34, 256, 0, stream>>>(Win, Wf, Wg1, Wg2, Wo, bg1, bg2, bo, wb, uv, cur);
  k_scatter<<<NB, 256, 0, stream>>>(src, dst, cur, packed, E);
  k_main<<<Gg + NP2, 256, 0, stream>>>(mf, fe, Wf, bin, wb, Wo, bo, q, Pm,
                                       packed, cur, rp, csr, N, Gg);
  k_gather1<<<Gt, 256, 0, stream>>>(rp, csr, q, uv, T2, N);
  k_gather2<<<Gt, 256, 0, stream>>>(rp, csr, T2, q, uv, Pm, out, N);
}